// Round 4
// baseline (94.540 us; speedup 1.0000x reference)
//
#include <hip/hip_runtime.h>

#define BB 32
#define QQ 16384
#define GG 128
#define KK 32
#define NN 9
#define TT 16       // GTs per K1 block
#define TH 1024     // K1 block size
#define HR 8        // elements per K1 thread (half-Q split)
#define NRANGE 2048 // ranges per (b, GT); range r covers {r + j*NRANGE, j<8}
#define RPL 32      // ranges per K2 lane (contiguous)
#define CAP 192     // per-GT candidate capacity (expected ~40 with tight U)
#define ACAP 96     // per-GT active-range capacity (expected ~36)
#define UF 4        // K1 load prefetch batch

typedef unsigned long long u64;
typedef unsigned int u32;

#define INFF __uint_as_float(0x7F800000u)

// packed ascending key: (float bits of nonneg key) << 32 | idx
// lexicographic u64 compare == (value asc, index asc) == jax top_k tie rule
__device__ __forceinline__ u64 pack_asc(float key, u32 idx) {
  return (((u64)__float_as_uint(key)) << 32) | (u64)idx;
}

// EXACT reference squared distance: ((dx^2+dy^2)+dz^2)+dw^2, no contraction.
// ref d = sqrtf(this).
__device__ __forceinline__ float dist2_ref(const float4 g, const float4 p) {
#pragma clang fp contract(off)
  float dx = g.x - p.x;
  float dy = g.y - p.y;
  float dz = g.z - p.z;
  float dw = g.w - p.w;
  float s = dx * dx + dy * dy;
  s = s + dz * dz;
  s = s + dw * dw;
  return s;
}

// IoU exactly as reference (cxcywh -> xyxy, clip, same op order)
__device__ __forceinline__ float iou_ref(const float4 g, const float4 p) {
#pragma clang fp contract(off)
  float gx1 = g.x - 0.5f * g.z, gy1 = g.y - 0.5f * g.w;
  float gx2 = g.x + 0.5f * g.z, gy2 = g.y + 0.5f * g.w;
  float px1 = p.x - 0.5f * p.z, py1 = p.y - 0.5f * p.w;
  float px2 = p.x + 0.5f * p.z, py2 = p.y + 0.5f * p.w;
  float ltx = fmaxf(gx1, px1), lty = fmaxf(gy1, py1);
  float rbx = fminf(gx2, px2), rby = fminf(gy2, py2);
  float wx = fmaxf(rbx - ltx, 0.0f), wy = fmaxf(rby - lty, 0.0f);
  float inter = wx * wy;
  float aa = (gx2 - gx1) * (gy2 - gy1);
  float ab = (px2 - px1) * (py2 - py1);
  return inter / ((aa + ab) - inter);
}

// monotone bijection float -> u32 (total order preserved; no NaN inputs)
__device__ __forceinline__ u32 f2ord(float f) {
  u32 b = __float_as_uint(f);
  return (b & 0x80000000u) ? ~b : (b | 0x80000000u);
}
__device__ __forceinline__ float ord2f(u32 k) {
  return __uint_as_float((k & 0x80000000u) ? (k & 0x7FFFFFFFu) : ~k);
}

// ================= K1: per-range min of s = |p|^2 - 2 g.p =================
// 512 blocks x 1024 thr; block = (batch b, GT-group m of 16, Q-half h).
// Thread t handles range r = h*1024 + t: elements {r + j*NRANGE, j<8}.
// No LDS, 2 blocks/CU, 8 waves/SIMD.
__global__ __launch_bounds__(TH, 8) void atss_phase1(
    const float4* __restrict__ pred, const float4* __restrict__ gtb,
    float* __restrict__ ws) {
  const int t = threadIdx.x;
  // XCD swizzle: f&7 = b>>2 -> same-batch blocks share an XCD (round-robin
  // dispatch assumed; perf-only). f = [b&3|h|m|b>>2] over 9 bits, bijective.
  const int f = blockIdx.x;
  const int b = (f & 7) * 4 + (f >> 7);
  const int m = (f >> 3) & 7;
  const int h = (f >> 6) & 1;
  const int g0 = m * TT;

  // 16 GT boxes from block-uniform addresses -> scalar loads / SGPRs
  float4 G[TT];
#pragma unroll
  for (int gg = 0; gg < TT; ++gg) G[gg] = gtb[b * GG + g0 + gg];

  const float4* pb = pred + (size_t)b * QQ;
  const int r = h * 1024 + t;  // this thread's range id

  float mn[TT];
#pragma unroll
  for (int gg = 0; gg < TT; ++gg) mn[gg] = INFF;

  float4 P[UF];
#pragma unroll
  for (int u = 0; u < UF; ++u) P[u] = pb[r + u * NRANGE];
#pragma unroll
  for (int j = 0; j < HR; j += UF) {
    float4 C[UF];
#pragma unroll
    for (int u = 0; u < UF; ++u) C[u] = P[u];
    if (j + UF < HR) {
#pragma unroll
      for (int u = 0; u < UF; ++u) P[u] = pb[r + (j + UF + u) * NRANGE];
    }
#pragma unroll
    for (int u = 0; u < UF; ++u) {
      float4 p = C[u];
      float pp = fmaf(p.x, p.x, fmaf(p.y, p.y, fmaf(p.z, p.z, p.w * p.w)));
      float qx = p.x + p.x, qy = p.y + p.y, qz = p.z + p.z, qw = p.w + p.w;
#pragma unroll
      for (int gg = 0; gg < TT; ++gg) {
        float acc = fmaf(-G[gg].x, qx, pp);
        acc = fmaf(-G[gg].y, qy, acc);
        acc = fmaf(-G[gg].z, qz, acc);
        acc = fmaf(-G[gg].w, qw, acc);
        mn[gg] = fminf(mn[gg], acc);
      }
    }
  }
  // ws layout: [(b*8 + m)*16 + gg][NRANGE], coalesced stores
  float* seg = ws + (size_t)((b * 8 + m) * TT) * NRANGE;
#pragma unroll
  for (int gg = 0; gg < TT; ++gg) seg[gg * NRANGE + r] = mn[gg];
}

// ================= K2: per-GT selection, one 64-lane wave =================
// 4096 blocks x 64 thr; 16 independent waves/CU (TLP hides chain latency).
__global__ __launch_bounds__(64, 4) void atss_phase2(
    const float4* __restrict__ pred, const float4* __restrict__ gtb,
    const float* __restrict__ ws, int* __restrict__ out) {
  __shared__ float ckey[CAP];
  __shared__ unsigned short cidx[CAP];
  __shared__ unsigned short sact[ACAP];
  __shared__ int kidx[KK];  // rare fallback paths only

  const int lane = threadIdx.x;
  // XCD swizzle consistent with K1: f&7 = b>>2.
  const int f = blockIdx.x;
  const int x = f & 7;
  const int j = f >> 3;
  const int b = x * 4 + (j & 3);
  const int g = j >> 2;
  const u64 below = (lane == 0) ? 0ull : ((1ull << lane) - 1ull);

  const float4 gt = gtb[b * GG + g];  // wave-uniform
  const float4* pb = pred + (size_t)b * QQ;
  const float* vsrc =
      ws + (size_t)((b * 8 + (g >> 4)) * TT + (g & 15)) * NRANGE;

  // ---- lane owns 32 CONTIGUOUS ranges [lane*RPL, lane*RPL+RPL) ----
  // (any disjoint partition is valid; contiguous -> float4 loads)
  float V[RPL];
  const float4* v4 = (const float4*)(vsrc + lane * RPL);
#pragma unroll
  for (int u = 0; u < RPL / 4; ++u) {
    float4 q = v4[u];
    V[4 * u + 0] = q.x;
    V[4 * u + 1] = q.y;
    V[4 * u + 2] = q.z;
    V[4 * u + 3] = q.w;
  }

  // ---- per-lane 2 smallest of its 32 values (branchless) ----
  float m1 = INFF, m2 = INFF;
#pragma unroll
  for (int k = 0; k < RPL; ++k) {
    float v = V[k];
    float nm1 = fminf(m1, v);
    m2 = fminf(m2, fmaxf(m1, v));
    m1 = nm1;
  }

  // ---- U = EXACT 32nd smallest of the 128 kept values (2 per lane) ----
  // Ballot radix-select. Bound argument: kept set is a subset of the 2048
  // range-mins; the 32 kept values <= U are 32 DISTINCT ranges' mins ->
  // >= 32 distinct elements have approx s <= U.
  u32 k1 = f2ord(m1), k2 = f2ord(m2);
  u32 pref = 0;
#pragma unroll
  for (int bit = 31; bit >= 0; --bit) {
    u32 tr = pref | (1u << bit);
    int c = __popcll(__ballot(k1 < tr)) + __popcll(__ballot(k2 < tr));
    if (c < 32) pref = tr;
  }
  float Us = ord2f(pref);  // wave-uniform

  float gg2 = fmaf(gt.x, gt.x,
              fmaf(gt.y, gt.y, fmaf(gt.z, gt.z, gt.w * gt.w)));
  // Inflation covers fma-form vs ref-form rounding and sqrt-collapse ties
  // (margins proven in R5-R8; 10x+ headroom retained).
  const float sUs = Us + fabsf(Us) * 2e-5f + 4e-6f;          // s-space test
  const float T = fmaxf(Us + gg2, 0.0f) * 1.00002f + 4e-6f;  // d2-space test

  // ---- compact active ranges via ballot (no LDS atomics) ----
  int na = 0;
#pragma unroll
  for (int k = 0; k < RPL; ++k) {
    bool c = V[k] <= sUs;
    u64 mask = __ballot(c);
    if (c) {
      int pos = na + __popcll(mask & below);
      if (pos < ACAP) sact[pos] = (unsigned short)(lane * RPL + k);
    }
    na += __popcll(mask);  // wave-uniform
  }

  // ---- exact-d2 collection; ballot-compacted, 4-slot pipelined ----
  int nCand = 0;
  if (na <= ACAP) {
    // item (entry e, element jj) with 8 lanes per entry (jj = lane&7 fixed
    // per lane); entries advance e0 + 8*slot + 32*trip. sact-read +
    // scattered VMEM for trip t+1 fly while trip t is processed.
    const int eo = (lane & 7) * NRANGE;
    const int e0 = lane >> 3;
    const int trips = (na + 31) >> 5;  // na >= 32 -> trips >= 1

#define ISSUE(ENT, VV, II, PP)                        \
  {                                                   \
    int ent_ = (ENT);                                 \
    VV = ent_ < na;                                   \
    int ecl_ = VV ? ent_ : 0;                         \
    II = (int)sact[ecl_] + eo;                        \
    PP = pb[II];                                      \
  }
#define PROCESS(VV, II, PP)                           \
  {                                                   \
    float d2_ = dist2_ref(gt, PP);                    \
    bool acc_ = VV && (d2_ <= T);                     \
    u64 mask_ = __ballot(acc_);                       \
    if (acc_) {                                       \
      int pos_ = nCand + __popcll(mask_ & below);     \
      if (pos_ < CAP) {                               \
        ckey[pos_] = d2_;                             \
        cidx[pos_] = (unsigned short)II;              \
      }                                               \
    }                                                 \
    nCand += __popcll(mask_);                         \
  }

    bool va, vb, vc, vd;
    int ia, ib, ic, id;
    float4 pa, pbx, pc, pd;
    ISSUE(e0, va, ia, pa);
    ISSUE(e0 + 8, vb, ib, pbx);
    ISSUE(e0 + 16, vc, ic, pc);
    ISSUE(e0 + 24, vd, id, pd);
    for (int tr = 0; tr < trips; ++tr) {
      int en = e0 + 32 * (tr + 1);
      bool nva, nvb, nvc, nvd;
      int nia, nib, nic, nid;
      float4 npa, npb, npc, npd;
      ISSUE(en, nva, nia, npa);
      ISSUE(en + 8, nvb, nib, npb);
      ISSUE(en + 16, nvc, nic, npc);
      ISSUE(en + 24, nvd, nid, npd);
      PROCESS(va, ia, pa);
      PROCESS(vb, ib, pbx);
      PROCESS(vc, ic, pc);
      PROCESS(vd, id, pd);
      va = nva; ia = nia; pa = npa;
      vb = nvb; ib = nib; pbx = npb;
      vc = nvc; ic = nic; pc = npc;
      vd = nvd; id = nid; pd = npd;
    }
#undef ISSUE
#undef PROCESS
  } else {
    // pathological: dense wave rescan of all ranges (ballot-compacted)
    for (int rr = 0; rr < RPL; ++rr) {
      int r = lane * RPL + rr;
      for (int jj = 0; jj < HR; ++jj) {
        int i = r + jj * NRANGE;
        float d2 = dist2_ref(gt, pb[i]);
        bool acc = d2 <= T;
        u64 mask = __ballot(acc);
        if (acc) {
          int pos = nCand + __popcll(mask & below);
          if (pos < CAP) {
            ckey[pos] = d2;
            cidx[pos] = (unsigned short)i;
          }
        }
        nCand += __popcll(mask);
      }
    }
  }
  const int n = nCand;  // wave-uniform; >= 32 guaranteed by the bound

  // ---- select top-32 by (d, idx) ascending; d = sqrtf(d2) (IEEE == jnp)
  int selIdx = 0;  // lane l<32 ends holding pred idx of K-position l
  if (n <= 64) {
    // fast path (~100%): in-register rank select; ONE ds_permute pushes
    // idx to lane==rank. Lanes >= n collide at lane n >= 32, never read.
    bool valid = lane < n;
    float myd = valid ? sqrtf(ckey[lane]) : 0.0f;
    u32 myi = valid ? (u32)cidx[lane] : 0u;
    u64 mk = valid ? pack_asc(myd, myi) : ~0ull;
    int rank = 0;
    for (int i = 0; i < n; ++i) {  // n uniform
      u64 ki = __shfl(mk, i, 64);
      rank += (ki < mk) ? 1 : 0;
    }
    selIdx = __builtin_amdgcn_ds_permute(rank << 2, (int)myi);
  } else if (n <= CAP) {
    // 64 < n <= CAP: 32 rounds of wave-wide argmin extraction (rare)
    volatile float* vk = ckey;
    for (int sel = 0; sel < KK; ++sel) {
      u64 lm = ~0ull;
      int ls = -1;
      for (int s = lane; s < n; s += 64) {
        float d = sqrtf(vk[s]);  // sqrtf(inf)=inf for consumed slots
        u64 pk = pack_asc(d, (u32)cidx[s]);
        if (pk < lm) {
          lm = pk;
          ls = s;
        }
      }
      u64 ww = lm;
#pragma unroll
      for (int jx = 32; jx > 0; jx >>= 1) {
        u64 o = __shfl_xor(ww, jx, 64);
        ww = o < ww ? o : ww;
      }
      if (lm == ww && ls >= 0) {  // unique winner (idx unique)
        vk[ls] = INFF;            // mark used
        kidx[sel] = (int)(ww & 0xFFFFFFFFull);
      }
    }
    selIdx = kidx[lane & 31];  // same-wave DS ordering
  } else {
    // pathological-only exact serial fallback
    if (lane == 0) {
      u64 best[KK];
      for (int l = 0; l < KK; ++l) best[l] = ~0ull;
      for (int i = 0; i < QQ; ++i) {
        float d = sqrtf(dist2_ref(gt, pb[i]));
        u64 pk = pack_asc(d, (u32)i);
        if (pk < best[KK - 1]) {
          int pos = KK - 1;
          while (pos > 0 && best[pos - 1] > pk) {
            best[pos] = best[pos - 1];
            --pos;
          }
          best[pos] = pk;
        }
      }
      for (int l = 0; l < KK; ++l) kidx[l] = (int)(best[l] & 0xFFFFFFFFull);
    }
    selIdx = kidx[lane & 31];  // same-wave DS ordering
  }

  // ---- IoU of the 32 candidates, top-9 by (iou desc, K-position asc) ----
  {
    float iou = 0.0f;
    u32 pi = 0;
    if (lane < KK) {
      pi = (u32)selIdx;
      iou = iou_ref(gt, pb[pi]);
    }
    // ~bits(iou) strictly decreasing in iou (iou >= 0): smaller key ==
    // higher iou; ties -> lower K-position (i < lane term).
    u32 ik = (lane < KK) ? ~__float_as_uint(iou) : 0xFFFFFFFFu;
    int r9 = 0;
    for (int i = 0; i < KK; ++i) {
      u32 ki = __shfl(ik, i, 64);
      r9 += ((ki < ik) || (ki == ik && i < lane)) ? 1 : 0;
    }
    if (lane < KK && r9 < NN) {
      int base = (b * GG + g) * NN + r9;
      out[base] = (int)pi;            // pred_idx
      out[BB * GG * NN + base] = g;   // gt_idx
    }
  }
}

extern "C" void kernel_launch(void* const* d_in, const int* in_sizes, int n_in,
                              void* d_out, int out_size, void* d_ws, size_t ws_size,
                              hipStream_t stream) {
  (void)in_sizes;
  (void)n_in;
  (void)out_size;
  (void)ws_size;
  const float4* pred = (const float4*)d_in[0];  // [B, Q, 4] f32
  const float4* gt = (const float4*)d_in[1];    // [B, G, 4] f32
  int* out = (int*)d_out;                       // [2 * B * G * N] int32
  float* ws = (float*)d_ws;                     // 16 MB of range-mins
  atss_phase1<<<512, TH, 0, stream>>>(pred, gt, ws);
  atss_phase2<<<4096, 64, 0, stream>>>(pred, gt, ws, out);
}